// Round 11
// baseline (416.194 us; speedup 1.0000x reference)
//
#include <hip/hip_runtime.h>
#include <hip/hip_bf16.h>

typedef unsigned short ushort_t;
typedef __attribute__((ext_vector_type(8))) short bf16x8;
typedef __attribute__((ext_vector_type(4))) float f32x4;
typedef __attribute__((ext_vector_type(16))) float f32x16;
typedef __attribute__((ext_vector_type(8))) unsigned short u16x8;
typedef __attribute__((ext_vector_type(4))) unsigned short u16x4;

#define NDIM 2048
#define BDIM 8

__device__ __forceinline__ float bf2f(unsigned short u) {
  union { unsigned int i; float f; } v; v.i = ((unsigned int)u) << 16; return v.f;
}
__device__ __forceinline__ unsigned short f2bf(float f) {
  union { float f; unsigned int i; } v; v.f = f;
  unsigned int x = v.i;
  x += 0x7fffu + ((x >> 16) & 1u);   // round to nearest even
  return (unsigned short)(x >> 16);
}

__device__ __forceinline__ void gload16(const void* g, void* l) {
  __builtin_amdgcn_global_load_lds(
      (const __attribute__((address_space(1))) void*)g,
      (__attribute__((address_space(3))) void*)l,
      16, 0, 0);
}

// ---------- elementwise f32 -> bf16 ----------
__global__ __launch_bounds__(256) void convert_bf16(const float* __restrict__ src,
                                                    unsigned short* __restrict__ dst, int n) {
  int i = (blockIdx.x * 256 + threadIdx.x) * 4;
  if (i < n) {
    f32x4 v = *(const f32x4*)&src[i];
    u16x4 w;
    #pragma unroll
    for (int k = 0; k < 4; ++k) w[k] = f2bf(v[k]);
    *(u16x4*)&dst[i] = w;
  }
}

// ---------- x [b][c][n] f32 -> cur_T [b][n][c] bf16 ----------
__global__ __launch_bounds__(256) void transpose_convert(const float* __restrict__ x,
                                                         unsigned short* __restrict__ dst) {
  __shared__ float tile[64][65];
  const int b  = blockIdx.z;
  const int n0 = blockIdx.x * 64;
  const int c0 = blockIdx.y * 64;
  const int tr = threadIdx.x >> 4;
  const int tc = threadIdx.x & 15;
  const float* src = x + ((size_t)b * NDIM + c0) * NDIM + n0;
  #pragma unroll
  for (int p = 0; p < 4; ++p) {
    int r = p * 16 + tr;
    f32x4 v = *(const f32x4*)&src[(size_t)r * NDIM + tc * 4];
    #pragma unroll
    for (int k = 0; k < 4; ++k) tile[r][tc * 4 + k] = v[k];
  }
  __syncthreads();
  unsigned short* d = dst + ((size_t)b * NDIM + n0) * NDIM + c0;
  #pragma unroll
  for (int p = 0; p < 4; ++p) {
    int r = p * 16 + tr;
    u16x4 w;
    #pragma unroll
    for (int k = 0; k < 4; ++k) w[k] = f2bf(tile[tc * 4 + k][r]);
    *(u16x4*)&d[(size_t)r * NDIM + tc * 4] = w;
  }
}

// ---------- wbeff = Wa^T Wb, wceff = Wa^T Wc ----------
__global__ __launch_bounds__(256) void weff1(const float* __restrict__ Wa,
                                             const float* __restrict__ Wb,
                                             const float* __restrict__ Wc,
                                             float* __restrict__ part) {
  int c  = blockIdx.x * 256 + threadIdx.x;
  int o0 = blockIdx.y * 128;
  float ab = 0.f, ac = 0.f;
  for (int o = o0; o < o0 + 128; ++o) {
    float w = Wa[(size_t)o * NDIM + c];
    ab = fmaf(Wb[o], w, ab);
    ac = fmaf(Wc[o], w, ac);
  }
  part[(size_t)(blockIdx.y * 2 + 0) * NDIM + c] = ab;
  part[(size_t)(blockIdx.y * 2 + 1) * NDIM + c] = ac;
}
__global__ __launch_bounds__(256) void weff2(const float* __restrict__ part,
                                             float* __restrict__ wbe, float* __restrict__ wce) {
  int c = blockIdx.x * 256 + threadIdx.x;
  float ab = 0.f, ac = 0.f;
  #pragma unroll
  for (int i = 0; i < 16; ++i) {
    ab += part[(size_t)(i * 2 + 0) * NDIM + c];
    ac += part[(size_t)(i * 2 + 1) * NDIM + c];
  }
  wbe[c] = ab; wce[c] = ac;
}

// ---------- t1[b,n], t2[b,n] ----------
__global__ __launch_bounds__(256) void t_kernel(const unsigned short* __restrict__ curT,
                                                const float* __restrict__ wbe,
                                                const float* __restrict__ wce,
                                                const float* __restrict__ bb,
                                                const float* __restrict__ bc,
                                                float* __restrict__ t1, float* __restrict__ t2) {
  int row  = blockIdx.x * 4 + (threadIdx.x >> 6);
  int lane = threadIdx.x & 63;
  const unsigned short* r = curT + (size_t)row * NDIM;
  float a1 = 0.f, a2 = 0.f;
  #pragma unroll
  for (int p = 0; p < 4; ++p) {
    int c0 = p * 512 + lane * 8;
    u16x8 v = *(const u16x8*)&r[c0];
    f32x4 w1a = *(const f32x4*)&wbe[c0];
    f32x4 w1b = *(const f32x4*)&wbe[c0 + 4];
    f32x4 w2a = *(const f32x4*)&wce[c0];
    f32x4 w2b = *(const f32x4*)&wce[c0 + 4];
    #pragma unroll
    for (int j = 0; j < 4; ++j) {
      float xv = bf2f(v[j]);
      a1 = fmaf(w1a[j], xv, a1);
      a2 = fmaf(w2a[j], xv, a2);
    }
    #pragma unroll
    for (int j = 0; j < 4; ++j) {
      float xv = bf2f(v[4 + j]);
      a1 = fmaf(w1b[j], xv, a1);
      a2 = fmaf(w2b[j], xv, a2);
    }
  }
  #pragma unroll
  for (int off = 32; off > 0; off >>= 1) {
    a1 += __shfl_xor(a1, off);
    a2 += __shfl_xor(a2, off);
  }
  if (lane == 0) { t1[row] = a1 + bb[0]; t2[row] = a2 + bc[0]; }
}

// ---------- S[o,n] = log sum_b exp(lrelu(t1[b,n]+t2[b,o])) ----------
__global__ __launch_bounds__(256) void s_kernel(const float* __restrict__ t1,
                                                const float* __restrict__ t2,
                                                float* __restrict__ S) {
  int n = blockIdx.x * 256 + threadIdx.x;
  int o = blockIdx.y;
  float acc = 0.f;
  #pragma unroll
  for (int b = 0; b < BDIM; ++b) {
    float z = t1[b * NDIM + n] + t2[b * NDIM + o];
    z = z >= 0.f ? z : 0.2f * z;
    acc += __expf(z);
  }
  S[(size_t)o * NDIM + n] = __logf(acc);
}

// ---------- fused GEMM + softmax-scale epilogue ----------
// Round-2 skeleton (256x256 tile, BK=32, 8 waves 2Mx4N, ring-4 LDS, counted
// vmcnt(8), 2 phases/K-tile) with MFMA shape switched to 32x32x16:
// per wave 4m x 2n f32x16 accs; phases split by k-step (ks=0 / ks=1).
// Staging + XOR swizzle identical to r2 (byte-balanced for 32x32 reads).
__global__ __launch_bounds__(512, 2) void gemm_fused(
    const unsigned short* __restrict__ A,    // Wa bf16 [2048][2048], k-contig
    const unsigned short* __restrict__ Bt,   // cur_T bf16 [8][2048][2048], k-contig
    const float* __restrict__ t1, const float* __restrict__ t2,
    const float* __restrict__ S,  const float* __restrict__ bias,
    unsigned short* __restrict__ outT,       // next cur_T (step 0)
    float* __restrict__ outF,                // d_out (step 1)
    int write_f32) {
  __shared__ __align__(16) unsigned short sbuf[4 * 16384];  // 128 KiB ring-4

  const int tid  = threadIdx.x;
  const int lane = tid & 63;
  const int w    = tid >> 6;           // wave 0..7
  const int wr   = w >> 2;             // 0..1  (M)
  const int wc   = w & 3;              // 0..3  (N)
  const int bn0  = blockIdx.x * 256;   // x fastest -> one bn panel per XCD
  const int bm0  = blockIdx.y * 256;
  const int bz   = blockIdx.z;
  const unsigned short* Bb = Bt + (size_t)bz * NDIM * NDIM;

  f32x16 acc[4][2];
  #pragma unroll
  for (int m = 0; m < 4; ++m)
    #pragma unroll
    for (int n = 0; n < 2; ++n)
      #pragma unroll
      for (int e = 0; e < 16; ++e) acc[m][n][e] = 0.f;

  // ---- staging decode (identical to r2): wave writes LDS linearly.
  // LDS row r (64B) phys slot s' is written by lane (r%16)*4 + s', loading
  // global logical slot s'^((r>>1)&3) (XOR involution).
  const int sr = lane >> 2;
  const int sc = lane & 3;
  const int r0 = (w * 2 + 0) * 16 + sr;
  const int r1 = (w * 2 + 1) * 16 + sr;
  const int sg = sc ^ ((r0 >> 1) & 3);  // rows differ by 16 -> same swizzle
  const unsigned short* a0 = A  + (size_t)(bm0 + r0) * NDIM + sg * 8;
  const unsigned short* a1 = A  + (size_t)(bm0 + r1) * NDIM + sg * 8;
  const unsigned short* b0 = Bb + (size_t)(bn0 + r0) * NDIM + sg * 8;
  const unsigned short* b1 = Bb + (size_t)(bn0 + r1) * NDIM + sg * 8;

  auto stageA = [&](int kt, int buf) {
    gload16(a0 + kt, &sbuf[buf * 16384 + (w * 2 + 0) * 512]);
    gload16(a1 + kt, &sbuf[buf * 16384 + (w * 2 + 1) * 512]);
  };
  auto stageB = [&](int kt, int buf) {
    gload16(b0 + kt, &sbuf[buf * 16384 + 8192 + (w * 2 + 0) * 512]);
    gload16(b1 + kt, &sbuf[buf * 16384 + 8192 + (w * 2 + 1) * 512]);
  };

  // ---- 32x32x16 fragment decode ----
  // A frag (m, ks): lane holds A[row=m*32+ar][k = ks*16 + kg*8 .. +8]
  //   ar = lane&31, kg = lane>>5. Logical 16B slot s = ks*2+kg, phys
  //   slot = s ^ ((row>>1)&3) = s ^ ((ar>>1)&3) (region bases mult. of 32).
  const int ar   = lane & 31;
  const int kg   = lane >> 5;
  const int arsw = (ar >> 1) & 3;
  const int spk0 = ((0 + kg) ^ arsw) * 8;   // ks=0, ushort offset in row
  const int spk1 = ((2 + kg) ^ arsw) * 8;   // ks=1

  // ---- prologue: stage tiles 0,1,2 ----
  stageA(0, 0);  stageB(0, 0);
  stageA(32, 1); stageB(32, 1);
  stageA(64, 2); stageB(64, 2);
  asm volatile("s_waitcnt vmcnt(8)" ::: "memory");   // tile 0 landed
  __builtin_amdgcn_s_barrier();

  // ---- main loop: 64 K-tiles, two pinned phases each (split by ks) ----
  for (int t4 = 0; t4 < 64; t4 += 4) {
    #pragma unroll
    for (int u = 0; u < 4; ++u) {
      const int t  = t4 + u;
      const int cb = u;                         // cur buf = t & 3
      const int nb = (u + 3) & 3;               // (t+3) & 3
      const int tc = (t + 3 > 63) ? 63 : (t + 3);   // clamp keeps vmcnt uniform
      const int ktn = tc * 32;
      const unsigned short* Ab = &sbuf[cb * 16384];
      const unsigned short* Bl = &sbuf[cb * 16384 + 8192];

      bf16x8 av[4], bv[2];
      // ======== phase A (ks=0): 6 reads, stage A(t+3), 8 MFMA ========
      #pragma unroll
      for (int m = 0; m < 4; ++m)
        av[m] = *(const bf16x8*)&Ab[(wr * 128 + m * 32 + ar) * 32 + spk0];
      #pragma unroll
      for (int n = 0; n < 2; ++n)
        bv[n] = *(const bf16x8*)&Bl[(wc * 64 + n * 32 + ar) * 32 + spk0];
      stageA(ktn, nb);
      __builtin_amdgcn_sched_barrier(0);
      __builtin_amdgcn_s_barrier();
      asm volatile("s_waitcnt lgkmcnt(0)" ::: "memory");
      __builtin_amdgcn_sched_barrier(0);       // rule #18
      __builtin_amdgcn_s_setprio(1);
      #pragma unroll
      for (int m = 0; m < 4; ++m)
        #pragma unroll
        for (int n = 0; n < 2; ++n)
          acc[m][n] = __builtin_amdgcn_mfma_f32_32x32x16_bf16(av[m], bv[n], acc[m][n], 0, 0, 0);
      __builtin_amdgcn_s_setprio(0);
      __builtin_amdgcn_sched_barrier(0);
      __builtin_amdgcn_s_barrier();

      // ======== phase B (ks=1): 6 reads, stage B(t+3), 8 MFMA ========
      #pragma unroll
      for (int m = 0; m < 4; ++m)
        av[m] = *(const bf16x8*)&Ab[(wr * 128 + m * 32 + ar) * 32 + spk1];
      #pragma unroll
      for (int n = 0; n < 2; ++n)
        bv[n] = *(const bf16x8*)&Bl[(wc * 64 + n * 32 + ar) * 32 + spk1];
      stageB(ktn, nb);
      __builtin_amdgcn_sched_barrier(0);
      __builtin_amdgcn_s_barrier();
      asm volatile("s_waitcnt lgkmcnt(0)" ::: "memory");
      __builtin_amdgcn_sched_barrier(0);
      __builtin_amdgcn_s_setprio(1);
      #pragma unroll
      for (int m = 0; m < 4; ++m)
        #pragma unroll
        for (int n = 0; n < 2; ++n)
          acc[m][n] = __builtin_amdgcn_mfma_f32_32x32x16_bf16(av[m], bv[n], acc[m][n], 0, 0, 0);
      __builtin_amdgcn_s_setprio(0);
      __builtin_amdgcn_sched_barrier(0);
      // counted wait: tiles t+2,t+3 (8 loads) stay in flight; t+1 landed
      asm volatile("s_waitcnt vmcnt(8)" ::: "memory");
      __builtin_amdgcn_s_barrier();
    }
  }

  // drain outstanding DMA before repurposing LDS
  asm volatile("s_waitcnt vmcnt(0)" ::: "memory");
  __syncthreads();

  // ---- epilogue ----
  float* sT1f = (float*)&sbuf[0];
  float* sT2f = sT1f + 256;
  if (tid < 256) sT1f[tid] = t1[bz * NDIM + bn0 + tid];
  else           sT2f[tid - 256] = t2[bz * NDIM + bm0 + (tid - 256)];
  __syncthreads();

  // C/D layout (verified m74/m101): col = lane&31, row = (r&3)+8*(r>>2)+4*kg
  const int kg4 = kg * 4;
  #pragma unroll
  for (int m = 0; m < 4; ++m) {
    #pragma unroll
    for (int n = 0; n < 2; ++n) {
      const int nn = wc * 64 + n * 32 + ar;     // local n (col)
      const int ng = bn0 + nn;
      const float tz1  = sT1f[nn];
      const float bval = bias[ng];
      #pragma unroll
      for (int g = 0; g < 4; ++g) {
        const int oo = wr * 128 + m * 32 + g * 8 + kg4;  // 4 consecutive rows
        const int o  = bm0 + oo;
        if (write_f32) {
          #pragma unroll
          for (int j = 0; j < 4; ++j) {
            float z = tz1 + sT2f[oo + j];
            z = z >= 0.f ? z : 0.2f * z;
            float coef = __expf(z - S[(size_t)(o + j) * NDIM + ng]);
            outF[(size_t)bz * NDIM * NDIM + (size_t)(o + j) * NDIM + ng] =
                fmaf(coef, acc[m][n][g * 4 + j], bval);
          }
        } else {
          u16x4 wv;
          #pragma unroll
          for (int j = 0; j < 4; ++j) {
            float z = tz1 + sT2f[oo + j];
            z = z >= 0.f ? z : 0.2f * z;
            float coef = __expf(z - S[(size_t)(o + j) * NDIM + ng]);
            wv[j] = f2bf(fmaf(coef, acc[m][n][g * 4 + j], bval));
          }
          *(u16x4*)&outT[(size_t)bz * NDIM * NDIM + (size_t)ng * NDIM + o] = wv;
        }
      }
    }
  }
}

extern "C" void kernel_launch(void* const* d_in, const int* in_sizes, int n_in,
                              void* d_out, int out_size, void* d_ws, size_t ws_size,
                              hipStream_t stream) {
  const float* x    = (const float*)d_in[0];
  const float* Wa   = (const float*)d_in[1];
  const float* Wb   = (const float*)d_in[2];
  const float* bb   = (const float*)d_in[3];
  const float* Wc   = (const float*)d_in[4];
  const float* bc   = (const float*)d_in[5];
  const float* bias = (const float*)d_in[6];
  float* out = (float*)d_out;

  char* ws = (char*)d_ws;
  unsigned short* curA = (unsigned short*)ws; ws += (size_t)BDIM * NDIM * NDIM * 2;
  unsigned short* curB = (unsigned short*)ws; ws += (size_t)BDIM * NDIM * NDIM * 2;
  unsigned short* WaB  = (unsigned short*)ws; ws += (size_t)NDIM * NDIM * 2;
  float* t1   = (float*)ws; ws += (size_t)BDIM * NDIM * 4;
  float* t2   = (float*)ws; ws += (size_t)BDIM * NDIM * 4;
  float* wbe  = (float*)ws; ws += NDIM * 4;
  float* wce  = (float*)ws; ws += NDIM * 4;
  float* part = (float*)ws; ws += (size_t)32 * NDIM * 4;
  float* S    = (float*)ws; ws += (size_t)NDIM * NDIM * 4;

  convert_bf16<<<4096, 256, 0, stream>>>(Wa, WaB, NDIM * NDIM);
  transpose_convert<<<dim3(32, 32, BDIM), 256, 0, stream>>>(x, curA);
  weff1<<<dim3(8, 16), 256, 0, stream>>>(Wa, Wb, Wc, part);
  weff2<<<8, 256, 0, stream>>>(part, wbe, wce);

  for (int step = 0; step < 2; ++step) {
    const unsigned short* cur = step ? curB : curA;
    t_kernel<<<(BDIM * NDIM) / 4, 256, 0, stream>>>(cur, wbe, wce, bb, bc, t1, t2);
    s_kernel<<<dim3(NDIM / 256, NDIM), 256, 0, stream>>>(t1, t2, S);
    gemm_fused<<<dim3(8, 8, BDIM), 512, 0, stream>>>(
        WaB, cur, t1, t2, S, bias, curB, out, step);
  }
}

// Round 12
// 366.993 us; speedup vs baseline: 1.1341x; 1.1341x over previous
//
#include <hip/hip_runtime.h>
#include <hip/hip_bf16.h>

typedef unsigned short ushort_t;
typedef __attribute__((ext_vector_type(8))) short bf16x8;
typedef __attribute__((ext_vector_type(4))) float f32x4;
typedef __attribute__((ext_vector_type(8))) unsigned short u16x8;
typedef __attribute__((ext_vector_type(4))) unsigned short u16x4;

#define NDIM 2048
#define BDIM 8

__device__ __forceinline__ float bf2f(unsigned short u) {
  union { unsigned int i; float f; } v; v.i = ((unsigned int)u) << 16; return v.f;
}
__device__ __forceinline__ unsigned short f2bf(float f) {
  union { float f; unsigned int i; } v; v.f = f;
  unsigned int x = v.i;
  x += 0x7fffu + ((x >> 16) & 1u);   // round to nearest even
  return (unsigned short)(x >> 16);
}

__device__ __forceinline__ void gload16(const void* g, void* l) {
  __builtin_amdgcn_global_load_lds(
      (const __attribute__((address_space(1))) void*)g,
      (__attribute__((address_space(3))) void*)l,
      16, 0, 0);
}

// ---------- Wa f32 -> fragment-packed bf16 A ----------
__global__ __launch_bounds__(256) void pack_a(const float* __restrict__ Wa,
                                              unsigned short* __restrict__ Apk) {
  const int sub = blockIdx.x * 4 + (threadIdx.x >> 6);   // 0..8191
  const int l   = threadIdx.x & 63;
  const int mt  = sub >> 6, kt = sub & 63;
  const int fr  = l & 15, fs = l >> 4;
  const float* src = Wa + (size_t)(mt * 16 + fr) * NDIM + kt * 32 + fs * 8;
  f32x4 v0 = *(const f32x4*)&src[0];
  f32x4 v1 = *(const f32x4*)&src[4];
  u16x8 w;
  #pragma unroll
  for (int k = 0; k < 4; ++k) { w[k] = f2bf(v0[k]); w[4 + k] = f2bf(v1[k]); }
  *(u16x8*)&Apk[(size_t)sub * 512 + l * 8] = w;
}

// ---------- x [b][c][n] f32 -> cur_T [b][n][c] bf16, fused t1/t2 partials ----
__global__ __launch_bounds__(256) void transpose_convert(
    const float* __restrict__ x, unsigned short* __restrict__ dst,
    const float* __restrict__ wbe, const float* __restrict__ wce,
    float* __restrict__ t1, float* __restrict__ t2) {
  __shared__ float tile[64][65];
  const int b  = blockIdx.z;
  const int n0 = blockIdx.x * 64;
  const int c0 = blockIdx.y * 64;
  const int tr = threadIdx.x >> 4;
  const int tc = threadIdx.x & 15;
  const float* src = x + ((size_t)b * NDIM + c0) * NDIM + n0;
  #pragma unroll
  for (int p = 0; p < 4; ++p) {
    int r = p * 16 + tr;
    f32x4 v = *(const f32x4*)&src[(size_t)r * NDIM + tc * 4];
    #pragma unroll
    for (int k = 0; k < 4; ++k) tile[r][tc * 4 + k] = v[k];
  }
  __syncthreads();
  float w1[4], w2[4];
  #pragma unroll
  for (int k = 0; k < 4; ++k) {
    w1[k] = wbe[c0 + tc * 4 + k];
    w2[k] = wce[c0 + tc * 4 + k];
  }
  unsigned short* d = dst + ((size_t)b * NDIM + n0) * NDIM + c0;
  #pragma unroll
  for (int p = 0; p < 4; ++p) {
    int r = p * 16 + tr;   // n-local
    u16x4 w;
    float a1 = 0.f, a2 = 0.f;
    #pragma unroll
    for (int k = 0; k < 4; ++k) {
      float v = tile[tc * 4 + k][r];
      w[k] = f2bf(v);
      a1 = fmaf(w1[k], v, a1);
      a2 = fmaf(w2[k], v, a2);
    }
    *(u16x4*)&d[(size_t)r * NDIM + tc * 4] = w;
    // reduce over tc (lane bits 0..3)
    a1 += __shfl_xor(a1, 1); a1 += __shfl_xor(a1, 2);
    a1 += __shfl_xor(a1, 4); a1 += __shfl_xor(a1, 8);
    a2 += __shfl_xor(a2, 1); a2 += __shfl_xor(a2, 2);
    a2 += __shfl_xor(a2, 4); a2 += __shfl_xor(a2, 8);
    if (tc == 0) {
      atomicAdd(&t1[(size_t)b * NDIM + n0 + r], a1);
      atomicAdd(&t2[(size_t)b * NDIM + n0 + r], a2);
    }
  }
}

// ---------- wbeff = Wa^T Wb, wceff = Wa^T Wc ----------
__global__ __launch_bounds__(256) void weff1(const float* __restrict__ Wa,
                                             const float* __restrict__ Wb,
                                             const float* __restrict__ Wc,
                                             float* __restrict__ part) {
  int c  = blockIdx.x * 256 + threadIdx.x;
  int o0 = blockIdx.y * 128;
  float ab = 0.f, ac = 0.f;
  for (int o = o0; o < o0 + 128; ++o) {
    float w = Wa[(size_t)o * NDIM + c];
    ab = fmaf(Wb[o], w, ab);
    ac = fmaf(Wc[o], w, ac);
  }
  part[(size_t)(blockIdx.y * 2 + 0) * NDIM + c] = ab;
  part[(size_t)(blockIdx.y * 2 + 1) * NDIM + c] = ac;
}
__global__ __launch_bounds__(256) void weff2(const float* __restrict__ part,
                                             float* __restrict__ wbe, float* __restrict__ wce) {
  int c = blockIdx.x * 256 + threadIdx.x;
  float ab = 0.f, ac = 0.f;
  #pragma unroll
  for (int i = 0; i < 16; ++i) {
    ab += part[(size_t)(i * 2 + 0) * NDIM + c];
    ac += part[(size_t)(i * 2 + 1) * NDIM + c];
  }
  wbe[c] = ab; wce[c] = ac;
}

// ---------- S[o,n] = log sum_b exp(lrelu(t1[b,n]+t2[b,o]+bb+bc)) ----------
__global__ __launch_bounds__(256) void s_kernel(const float* __restrict__ t1,
                                                const float* __restrict__ t2,
                                                const float* __restrict__ bb,
                                                const float* __restrict__ bc,
                                                float* __restrict__ S) {
  int n = blockIdx.x * 256 + threadIdx.x;
  int o = blockIdx.y;
  const float bias2 = bb[0] + bc[0];
  float acc = 0.f;
  #pragma unroll
  for (int b = 0; b < BDIM; ++b) {
    float z = t1[b * NDIM + n] + t2[b * NDIM + o] + bias2;
    z = z >= 0.f ? z : 0.2f * z;
    acc += __expf(z);
  }
  S[(size_t)o * NDIM + n] = __logf(acc);
}

// ---------- fused GEMM + softmax-scale epilogue (+ next-step t partials) ----
// r10 structure: 256x256 tile, BK=64, 8 waves (2M x 4N). A-fragments direct
// global->VGPR (fragment-packed); B via global_load_lds, 2x32KB dbuf; one
// barrier per K-tile, counted vmcnt gates. Step-0 epilogue also accumulates
// t1/t2 partials for the next step (wbe/wce dot over o, atomicAdd).
__global__ __launch_bounds__(512, 2) void gemm_fused(
    const unsigned short* __restrict__ Apk,  // packed A frags, 8 MB
    const unsigned short* __restrict__ Bt,   // cur_T bf16 [8][2048][2048]
    const float* __restrict__ t1, const float* __restrict__ t2,
    const float* __restrict__ bb, const float* __restrict__ bc,
    const float* __restrict__ S,  const float* __restrict__ bias,
    const float* __restrict__ wbe, const float* __restrict__ wce,
    float* __restrict__ t1o, float* __restrict__ t2o,
    unsigned short* __restrict__ outT,
    float* __restrict__ outF,
    int write_f32) {
  __shared__ __align__(16) unsigned short sbuf[2][16384];  // 2 x 32 KiB (B only)

  const int tid  = threadIdx.x;
  const int lane = tid & 63;
  const int w    = tid >> 6;
  const int wr   = w >> 2;             // 0..1
  const int wc   = w & 3;              // 0..3
  const int bn0  = blockIdx.x * 256;   // bn fastest -> one B panel per XCD
  const int bm0  = blockIdx.y * 256;
  const int bz   = blockIdx.z;
  const unsigned short* Bb = Bt + (size_t)bz * NDIM * NDIM;

  f32x4 acc[8][4];
  #pragma unroll
  for (int m = 0; m < 8; ++m)
    #pragma unroll
    for (int n = 0; n < 4; ++n) acc[m][n] = (f32x4){0.f, 0.f, 0.f, 0.f};

  // ---- B staging decode (rows 128 B, slot-XOR swizzle, linear DMA dest) ----
  const int sst   = (lane & 7) ^ (lane >> 3);
  const int srowl = lane >> 3;
  const unsigned short* bG = Bb + (size_t)(bn0 + w * 32 + srowl) * NDIM + sst * 8;
  auto stB = [&](int T, int p, int d) {   // one gload = 8 rows
    gload16(bG + (size_t)p * 8 * NDIM + T * 64, &sbuf[d][(w * 32 + p * 8) * 64]);
  };

  // ---- B fragment decode (swizzled read) ----
  const int fr  = lane & 15;
  const int fs  = lane >> 4;
  const int sl0 = ((fs) ^ (fr & 7)) * 8;
  const int sl1 = ((4 + fs) ^ (fr & 7)) * 8;
  const int bRow = (wc * 64 + fr) * 64;

  // ---- A fragment global offsets: blob (mt*64 + kt)*1024 + lane*16 ----
  const unsigned int mtBase = (unsigned)((bm0 >> 4) + wr * 8);
  unsigned int aOff0[4], aOff1[4];
  #pragma unroll
  for (int m = 0; m < 4; ++m) {
    aOff0[m] = ((mtBase + m) * 64u) * 1024u + lane * 16u;
    aOff1[m] = ((mtBase + 4 + m) * 64u) * 1024u + lane * 16u;
  }

  bf16x8 Am0[4][2], Am1[4][2], bv[2][2];

  auto issueA = [&](bf16x8 (&dst)[4][2], const unsigned int (&off)[4]) {
    #pragma unroll
    for (int m = 0; m < 4; ++m) {
      asm volatile("global_load_dwordx4 %0, %1, %2"
                   : "=v"(dst[m][0]) : "v"(off[m]), "s"(Apk) : "memory");
      asm volatile("global_load_dwordx4 %0, %1, %2 offset:1024"
                   : "=v"(dst[m][1]) : "v"(off[m]), "s"(Apk) : "memory");
    }
  };
  auto rdB = [&](int nh, int d) {
    #pragma unroll
    for (int n = 0; n < 2; ++n) {
      const int base = d * 16384 + bRow + (nh * 2 + n) * 16 * 64;
      bv[n][0] = *(const bf16x8*)&sbuf[0][base + sl0];
      bv[n][1] = *(const bf16x8*)&sbuf[0][base + sl1];
    }
  };
  auto quad = [&](bf16x8 (&af)[4][2], int mo, int no) {
    __builtin_amdgcn_s_setprio(1);
    #pragma unroll
    for (int m = 0; m < 4; ++m)
      #pragma unroll
      for (int n = 0; n < 2; ++n)
        #pragma unroll
        for (int ks = 0; ks < 2; ++ks)
          acc[mo + m][no + n] = __builtin_amdgcn_mfma_f32_16x16x32_bf16(
              af[m][ks], bv[n][ks], acc[mo + m][no + n], 0, 0, 0);
    __builtin_amdgcn_s_setprio(0);
    __builtin_amdgcn_sched_barrier(0);
  };

  // ---- prologue: B[0] -> buf0; A-mh0[0]; B landed, A in flight ----
  stB(0, 0, 0); stB(0, 1, 0); stB(0, 2, 0); stB(0, 3, 0);
  issueA(Am0, aOff0);
  asm volatile("s_waitcnt vmcnt(8)" ::: "memory");
  __builtin_amdgcn_s_barrier();

  // ---- main loop: 32 K-tiles, 2-tile unrolled for compile-time buf parity --
  #pragma clang loop unroll(disable)
  for (int tt = 0; tt < 16; ++tt) {
    const int Tn0 = 2 * tt + 1;
    const int Tn1 = (tt == 15) ? 31 : 2 * tt + 2;

    #pragma unroll
    for (int half = 0; half < 2; ++half) {
      const int cur = half, nxt = half ^ 1;
      const int Tn = half ? Tn1 : Tn0;

      // phi0: issue A-mh1[t]; read B nh0; gate(A-mh0 landed); MFMA (mh0,nh0)
      issueA(Am1, aOff1);
      #pragma unroll
      for (int m = 0; m < 4; ++m) aOff1[m] += 2048u;
      rdB(0, cur);
      asm volatile("s_waitcnt vmcnt(8)" ::: "memory");
      __builtin_amdgcn_sched_barrier(0);             // rule #18
      quad(Am0, 0, 0);

      // phi1: issue B[t+1] pair-a; gate(A-mh1 landed); MFMA (mh1,nh0)
      stB(Tn, 0, nxt); stB(Tn, 1, nxt);
      asm volatile("s_waitcnt vmcnt(2)" ::: "memory");
      __builtin_amdgcn_sched_barrier(0);
      quad(Am1, 4, 0);

      // phi2: issue B[t+1] pair-b; read B nh1; MFMA (mh0,nh1)
      stB(Tn, 2, nxt); stB(Tn, 3, nxt);
      rdB(1, cur);
      #pragma unroll
      for (int m = 0; m < 4; ++m) aOff0[m] += 2048u;
      __builtin_amdgcn_sched_barrier(0);
      quad(Am0, 0, 2);

      // phi3: issue A-mh0[t+1]; MFMA (mh1,nh1)
      issueA(Am0, aOff0);
      __builtin_amdgcn_sched_barrier(0);
      quad(Am1, 4, 2);

      // tile end: both B pairs landed; barrier
      asm volatile("s_waitcnt vmcnt(8)" ::: "memory");
      __builtin_amdgcn_s_barrier();
    }
  }

  asm volatile("s_waitcnt vmcnt(0)" ::: "memory");
  __syncthreads();

  // ---- epilogue ----
  float* sT1f = (float*)&sbuf[0][0];
  float* sT2f = sT1f + 256;
  if (tid < 256) sT1f[tid] = t1[bz * NDIM + bn0 + tid] + bb[0];
  else           sT2f[tid - 256] = t2[bz * NDIM + bm0 + (tid - 256)] + bc[0];
  __syncthreads();

  const int lr4 = fs * 4;
  if (write_f32) {
    #pragma unroll
    for (int m = 0; m < 8; ++m) {
      const int oo = wr * 128 + m * 16 + lr4;
      const int o  = bm0 + oo;
      #pragma unroll
      for (int n = 0; n < 4; ++n) {
        const int nn = wc * 64 + n * 16 + fr;
        const int ng = bn0 + nn;
        const float tz1  = sT1f[nn];
        const float bval = bias[ng];
        #pragma unroll
        for (int r = 0; r < 4; ++r) {
          float z = tz1 + sT2f[oo + r];
          z = z >= 0.f ? z : 0.2f * z;
          float coef = __expf(z - S[(size_t)(o + r) * NDIM + ng]);
          outF[(size_t)bz * NDIM * NDIM + (size_t)(o + r) * NDIM + ng] =
              fmaf(coef, acc[m][n][r], bval);
        }
      }
    }
  } else {
    float tp1[4] = {0.f, 0.f, 0.f, 0.f}, tp2[4] = {0.f, 0.f, 0.f, 0.f};
    #pragma unroll
    for (int m = 0; m < 8; ++m) {
      const int oo = wr * 128 + m * 16 + lr4;
      const int o  = bm0 + oo;
      float w1[4], w2[4];
      #pragma unroll
      for (int r = 0; r < 4; ++r) { w1[r] = wbe[o + r]; w2[r] = wce[o + r]; }
      #pragma unroll
      for (int n = 0; n < 4; ++n) {
        const int nn = wc * 64 + n * 16 + fr;
        const int ng = bn0 + nn;
        const float tz1  = sT1f[nn];
        const float bval = bias[ng];
        u16x4 wv;
        #pragma unroll
        for (int r = 0; r < 4; ++r) {
          float z = tz1 + sT2f[oo + r];
          z = z >= 0.f ? z : 0.2f * z;
          float coef = __expf(z - S[(size_t)(o + r) * NDIM + ng]);
          float val  = fmaf(coef, acc[m][n][r], bval);
          wv[r] = f2bf(val);
          tp1[n] = fmaf(w1[r], val, tp1[n]);
          tp2[n] = fmaf(w2[r], val, tp2[n]);
        }
        *(u16x4*)&outT[(size_t)bz * NDIM * NDIM + (size_t)ng * NDIM + o] = wv;
      }
    }
    // reduce t partials across fs (lanes {fr, fr+16, fr+32, fr+48}) + atomic
    #pragma unroll
    for (int n = 0; n < 4; ++n) {
      float a1 = tp1[n], a2 = tp2[n];
      a1 += __shfl_xor(a1, 16); a1 += __shfl_xor(a1, 32);
      a2 += __shfl_xor(a2, 16); a2 += __shfl_xor(a2, 32);
      if (fs == 0) {
        const int ng = bn0 + wc * 64 + n * 16 + fr;
        atomicAdd(&t1o[(size_t)bz * NDIM + ng], a1);
        atomicAdd(&t2o[(size_t)bz * NDIM + ng], a2);
      }
    }
  }
}

extern "C" void kernel_launch(void* const* d_in, const int* in_sizes, int n_in,
                              void* d_out, int out_size, void* d_ws, size_t ws_size,
                              hipStream_t stream) {
  const float* x    = (const float*)d_in[0];
  const float* Wa   = (const float*)d_in[1];
  const float* Wb   = (const float*)d_in[2];
  const float* bb   = (const float*)d_in[3];
  const float* Wc   = (const float*)d_in[4];
  const float* bc   = (const float*)d_in[5];
  const float* bias = (const float*)d_in[6];
  float* out = (float*)d_out;

  char* ws = (char*)d_ws;
  unsigned short* curA = (unsigned short*)ws; ws += (size_t)BDIM * NDIM * NDIM * 2;
  unsigned short* curB = (unsigned short*)ws; ws += (size_t)BDIM * NDIM * NDIM * 2;
  unsigned short* Apk  = (unsigned short*)ws; ws += (size_t)NDIM * NDIM * 2;
  float* t1a  = (float*)ws; ws += (size_t)BDIM * NDIM * 4;
  float* t2a  = (float*)ws; ws += (size_t)BDIM * NDIM * 4;
  float* t1b  = (float*)ws; ws += (size_t)BDIM * NDIM * 4;
  float* t2b  = (float*)ws; ws += (size_t)BDIM * NDIM * 4;
  float* wbe  = (float*)ws; ws += NDIM * 4;
  float* wce  = (float*)ws; ws += NDIM * 4;
  float* part = (float*)ws; ws += (size_t)32 * NDIM * 4;
  float* S    = (float*)ws; ws += (size_t)NDIM * NDIM * 4;

  hipMemsetAsync(t1a, 0, (size_t)BDIM * NDIM * 4, stream);
  hipMemsetAsync(t2a, 0, (size_t)BDIM * NDIM * 4, stream);
  hipMemsetAsync(t1b, 0, (size_t)BDIM * NDIM * 4, stream);
  hipMemsetAsync(t2b, 0, (size_t)BDIM * NDIM * 4, stream);

  pack_a<<<2048, 256, 0, stream>>>(Wa, Apk);
  weff1<<<dim3(8, 16), 256, 0, stream>>>(Wa, Wb, Wc, part);
  weff2<<<8, 256, 0, stream>>>(part, wbe, wce);
  transpose_convert<<<dim3(32, 32, BDIM), 256, 0, stream>>>(x, curA, wbe, wce, t1a, t2a);

  // step 0: curA -> curB (bf16 transposed), accumulate t1b/t2b
  s_kernel<<<dim3(NDIM / 256, NDIM), 256, 0, stream>>>(t1a, t2a, bb, bc, S);
  gemm_fused<<<dim3(8, 8, BDIM), 512, 0, stream>>>(
      Apk, curA, t1a, t2a, bb, bc, S, bias, wbe, wce, t1b, t2b, curB, out, 0);

  // step 1: curB -> out (f32)
  s_kernel<<<dim3(NDIM / 256, NDIM), 256, 0, stream>>>(t1b, t2b, bb, bc, S);
  gemm_fused<<<dim3(8, 8, BDIM), 512, 0, stream>>>(
      Apk, curB, t1b, t2b, bb, bc, S, bias, wbe, wce, t1a, t2a, curB, out, 1);
}

// Round 13
// 361.279 us; speedup vs baseline: 1.1520x; 1.0158x over previous
//
#include <hip/hip_runtime.h>
#include <hip/hip_bf16.h>

typedef unsigned short ushort_t;
typedef __attribute__((ext_vector_type(8))) short bf16x8;
typedef __attribute__((ext_vector_type(4))) float f32x4;
typedef __attribute__((ext_vector_type(8))) unsigned short u16x8;
typedef __attribute__((ext_vector_type(4))) unsigned short u16x4;

#define NDIM 2048
#define BDIM 8

__device__ __forceinline__ float bf2f(unsigned short u) {
  union { unsigned int i; float f; } v; v.i = ((unsigned int)u) << 16; return v.f;
}
__device__ __forceinline__ unsigned short f2bf(float f) {
  union { float f; unsigned int i; } v; v.f = f;
  unsigned int x = v.i;
  x += 0x7fffu + ((x >> 16) & 1u);   // round to nearest even
  return (unsigned short)(x >> 16);
}

__device__ __forceinline__ void gload16(const void* g, void* l) {
  __builtin_amdgcn_global_load_lds(
      (const __attribute__((address_space(1))) void*)g,
      (__attribute__((address_space(3))) void*)l,
      16, 0, 0);
}

// ---------- Wa f32 -> fragment-packed bf16 A ----------
__global__ __launch_bounds__(256) void pack_a(const float* __restrict__ Wa,
                                              unsigned short* __restrict__ Apk) {
  const int sub = blockIdx.x * 4 + (threadIdx.x >> 6);   // 0..8191
  const int l   = threadIdx.x & 63;
  const int mt  = sub >> 6, kt = sub & 63;
  const int fr  = l & 15, fs = l >> 4;
  const float* src = Wa + (size_t)(mt * 16 + fr) * NDIM + kt * 32 + fs * 8;
  f32x4 v0 = *(const f32x4*)&src[0];
  f32x4 v1 = *(const f32x4*)&src[4];
  u16x8 w;
  #pragma unroll
  for (int k = 0; k < 4; ++k) { w[k] = f2bf(v0[k]); w[4 + k] = f2bf(v1[k]); }
  *(u16x8*)&Apk[(size_t)sub * 512 + l * 8] = w;
}

// ---------- x [b][c][n] f32 -> cur_T [b][n][c] bf16, fused t1/t2 partials ----
__global__ __launch_bounds__(256) void transpose_convert(
    const float* __restrict__ x, unsigned short* __restrict__ dst,
    const float* __restrict__ wbe, const float* __restrict__ wce,
    float* __restrict__ t1, float* __restrict__ t2) {
  __shared__ float tile[64][65];
  const int b  = blockIdx.z;
  const int n0 = blockIdx.x * 64;
  const int c0 = blockIdx.y * 64;
  const int tr = threadIdx.x >> 4;
  const int tc = threadIdx.x & 15;
  const float* src = x + ((size_t)b * NDIM + c0) * NDIM + n0;
  #pragma unroll
  for (int p = 0; p < 4; ++p) {
    int r = p * 16 + tr;
    f32x4 v = *(const f32x4*)&src[(size_t)r * NDIM + tc * 4];
    #pragma unroll
    for (int k = 0; k < 4; ++k) tile[r][tc * 4 + k] = v[k];
  }
  __syncthreads();
  float w1[4], w2[4];
  #pragma unroll
  for (int k = 0; k < 4; ++k) {
    w1[k] = wbe[c0 + tc * 4 + k];
    w2[k] = wce[c0 + tc * 4 + k];
  }
  unsigned short* d = dst + ((size_t)b * NDIM + n0) * NDIM + c0;
  #pragma unroll
  for (int p = 0; p < 4; ++p) {
    int r = p * 16 + tr;   // n-local
    u16x4 w;
    float a1 = 0.f, a2 = 0.f;
    #pragma unroll
    for (int k = 0; k < 4; ++k) {
      float v = tile[tc * 4 + k][r];
      w[k] = f2bf(v);
      a1 = fmaf(w1[k], v, a1);
      a2 = fmaf(w2[k], v, a2);
    }
    *(u16x4*)&d[(size_t)r * NDIM + tc * 4] = w;
    a1 += __shfl_xor(a1, 1); a1 += __shfl_xor(a1, 2);
    a1 += __shfl_xor(a1, 4); a1 += __shfl_xor(a1, 8);
    a2 += __shfl_xor(a2, 1); a2 += __shfl_xor(a2, 2);
    a2 += __shfl_xor(a2, 4); a2 += __shfl_xor(a2, 8);
    if (tc == 0) {
      atomicAdd(&t1[(size_t)b * NDIM + n0 + r], a1);
      atomicAdd(&t2[(size_t)b * NDIM + n0 + r], a2);
    }
  }
}

// ---------- wbeff = Wa^T Wb, wceff = Wa^T Wc ----------
__global__ __launch_bounds__(256) void weff1(const float* __restrict__ Wa,
                                             const float* __restrict__ Wb,
                                             const float* __restrict__ Wc,
                                             float* __restrict__ part) {
  int c  = blockIdx.x * 256 + threadIdx.x;
  int o0 = blockIdx.y * 128;
  float ab = 0.f, ac = 0.f;
  for (int o = o0; o < o0 + 128; ++o) {
    float w = Wa[(size_t)o * NDIM + c];
    ab = fmaf(Wb[o], w, ab);
    ac = fmaf(Wc[o], w, ac);
  }
  part[(size_t)(blockIdx.y * 2 + 0) * NDIM + c] = ab;
  part[(size_t)(blockIdx.y * 2 + 1) * NDIM + c] = ac;
}
__global__ __launch_bounds__(256) void weff2(const float* __restrict__ part,
                                             float* __restrict__ wbe, float* __restrict__ wce) {
  int c = blockIdx.x * 256 + threadIdx.x;
  float ab = 0.f, ac = 0.f;
  #pragma unroll
  for (int i = 0; i < 16; ++i) {
    ab += part[(size_t)(i * 2 + 0) * NDIM + c];
    ac += part[(size_t)(i * 2 + 1) * NDIM + c];
  }
  wbe[c] = ab; wce[c] = ac;
}

// ---------- S[o,n] = log sum_b exp(lrelu(t1[b,n]+t2[b,o]+bb+bc)) ----------
__global__ __launch_bounds__(256) void s_kernel(const float* __restrict__ t1,
                                                const float* __restrict__ t2,
                                                const float* __restrict__ bb,
                                                const float* __restrict__ bc,
                                                float* __restrict__ S) {
  int n = blockIdx.x * 256 + threadIdx.x;
  int o = blockIdx.y;
  const float bias2 = bb[0] + bc[0];
  float acc = 0.f;
  #pragma unroll
  for (int b = 0; b < BDIM; ++b) {
    float z = t1[b * NDIM + n] + t2[b * NDIM + o] + bias2;
    z = z >= 0.f ? z : 0.2f * z;
    acc += __expf(z);
  }
  S[(size_t)o * NDIM + n] = __logf(acc);
}

// ---------- fused GEMM + softmax-scale epilogue (+ next-step t partials) ----
// r12 structure; only change: quad() iterates ks OUTERMOST so the two MFMAs
// touching the same acc[m][n] are 8 apart (dependency distance 8, was 1).
// Summation order per acc element unchanged (ks0 then ks1) => bit-identical.
__global__ __launch_bounds__(512, 2) void gemm_fused(
    const unsigned short* __restrict__ Apk,  // packed A frags, 8 MB
    const unsigned short* __restrict__ Bt,   // cur_T bf16 [8][2048][2048]
    const float* __restrict__ t1, const float* __restrict__ t2,
    const float* __restrict__ bb, const float* __restrict__ bc,
    const float* __restrict__ S,  const float* __restrict__ bias,
    const float* __restrict__ wbe, const float* __restrict__ wce,
    float* __restrict__ t1o, float* __restrict__ t2o,
    unsigned short* __restrict__ outT,
    float* __restrict__ outF,
    int write_f32) {
  __shared__ __align__(16) unsigned short sbuf[2][16384];  // 2 x 32 KiB (B only)

  const int tid  = threadIdx.x;
  const int lane = tid & 63;
  const int w    = tid >> 6;
  const int wr   = w >> 2;             // 0..1
  const int wc   = w & 3;              // 0..3
  const int bn0  = blockIdx.x * 256;
  const int bm0  = blockIdx.y * 256;
  const int bz   = blockIdx.z;
  const unsigned short* Bb = Bt + (size_t)bz * NDIM * NDIM;

  f32x4 acc[8][4];
  #pragma unroll
  for (int m = 0; m < 8; ++m)
    #pragma unroll
    for (int n = 0; n < 4; ++n) acc[m][n] = (f32x4){0.f, 0.f, 0.f, 0.f};

  // ---- B staging decode (rows 128 B, slot-XOR swizzle, linear DMA dest) ----
  const int sst   = (lane & 7) ^ (lane >> 3);
  const int srowl = lane >> 3;
  const unsigned short* bG = Bb + (size_t)(bn0 + w * 32 + srowl) * NDIM + sst * 8;
  auto stB = [&](int T, int p, int d) {   // one gload = 8 rows
    gload16(bG + (size_t)p * 8 * NDIM + T * 64, &sbuf[d][(w * 32 + p * 8) * 64]);
  };

  // ---- B fragment decode (swizzled read) ----
  const int fr  = lane & 15;
  const int fs  = lane >> 4;
  const int sl0 = ((fs) ^ (fr & 7)) * 8;
  const int sl1 = ((4 + fs) ^ (fr & 7)) * 8;
  const int bRow = (wc * 64 + fr) * 64;

  // ---- A fragment global offsets: blob (mt*64 + kt)*1024 + lane*16 ----
  const unsigned int mtBase = (unsigned)((bm0 >> 4) + wr * 8);
  unsigned int aOff0[4], aOff1[4];
  #pragma unroll
  for (int m = 0; m < 4; ++m) {
    aOff0[m] = ((mtBase + m) * 64u) * 1024u + lane * 16u;
    aOff1[m] = ((mtBase + 4 + m) * 64u) * 1024u + lane * 16u;
  }

  bf16x8 Am0[4][2], Am1[4][2], bv[2][2];

  auto issueA = [&](bf16x8 (&dst)[4][2], const unsigned int (&off)[4]) {
    #pragma unroll
    for (int m = 0; m < 4; ++m) {
      asm volatile("global_load_dwordx4 %0, %1, %2"
                   : "=v"(dst[m][0]) : "v"(off[m]), "s"(Apk) : "memory");
      asm volatile("global_load_dwordx4 %0, %1, %2 offset:1024"
                   : "=v"(dst[m][1]) : "v"(off[m]), "s"(Apk) : "memory");
    }
  };
  auto rdB = [&](int nh, int d) {
    #pragma unroll
    for (int n = 0; n < 2; ++n) {
      const int base = d * 16384 + bRow + (nh * 2 + n) * 16 * 64;
      bv[n][0] = *(const bf16x8*)&sbuf[0][base + sl0];
      bv[n][1] = *(const bf16x8*)&sbuf[0][base + sl1];
    }
  };
  // ks OUTERMOST: 8 independent MFMAs per ks pass; each acc written twice,
  // 8 apart. Per-element order still ks0 -> ks1 (bit-identical result).
  auto quad = [&](bf16x8 (&af)[4][2], int mo, int no) {
    __builtin_amdgcn_s_setprio(1);
    #pragma unroll
    for (int ks = 0; ks < 2; ++ks)
      #pragma unroll
      for (int m = 0; m < 4; ++m)
        #pragma unroll
        for (int n = 0; n < 2; ++n)
          acc[mo + m][no + n] = __builtin_amdgcn_mfma_f32_16x16x32_bf16(
              af[m][ks], bv[n][ks], acc[mo + m][no + n], 0, 0, 0);
    __builtin_amdgcn_s_setprio(0);
    __builtin_amdgcn_sched_barrier(0);
  };

  // ---- prologue: B[0] -> buf0; A-mh0[0]; B landed, A in flight ----
  stB(0, 0, 0); stB(0, 1, 0); stB(0, 2, 0); stB(0, 3, 0);
  issueA(Am0, aOff0);
  asm volatile("s_waitcnt vmcnt(8)" ::: "memory");
  __builtin_amdgcn_s_barrier();

  // ---- main loop: 32 K-tiles, 2-tile unrolled for compile-time buf parity --
  #pragma clang loop unroll(disable)
  for (int tt = 0; tt < 16; ++tt) {
    const int Tn0 = 2 * tt + 1;
    const int Tn1 = (tt == 15) ? 31 : 2 * tt + 2;

    #pragma unroll
    for (int half = 0; half < 2; ++half) {
      const int cur = half, nxt = half ^ 1;
      const int Tn = half ? Tn1 : Tn0;

      // phi0: issue A-mh1[t]; read B nh0; gate(A-mh0 landed); MFMA (mh0,nh0)
      issueA(Am1, aOff1);
      #pragma unroll
      for (int m = 0; m < 4; ++m) aOff1[m] += 2048u;
      rdB(0, cur);
      asm volatile("s_waitcnt vmcnt(8)" ::: "memory");
      __builtin_amdgcn_sched_barrier(0);             // rule #18
      quad(Am0, 0, 0);

      // phi1: issue B[t+1] pair-a; gate(A-mh1 landed); MFMA (mh1,nh0)
      stB(Tn, 0, nxt); stB(Tn, 1, nxt);
      asm volatile("s_waitcnt vmcnt(2)" ::: "memory");
      __builtin_amdgcn_sched_barrier(0);
      quad(Am1, 4, 0);

      // phi2: issue B[t+1] pair-b; read B nh1; MFMA (mh0,nh1)
      stB(Tn, 2, nxt); stB(Tn, 3, nxt);
      rdB(1, cur);
      #pragma unroll
      for (int m = 0; m < 4; ++m) aOff0[m] += 2048u;
      __builtin_amdgcn_sched_barrier(0);
      quad(Am0, 0, 2);

      // phi3: issue A-mh0[t+1]; MFMA (mh1,nh1)
      issueA(Am0, aOff0);
      __builtin_amdgcn_sched_barrier(0);
      quad(Am1, 4, 2);

      // tile end: both B pairs landed; barrier
      asm volatile("s_waitcnt vmcnt(8)" ::: "memory");
      __builtin_amdgcn_s_barrier();
    }
  }

  asm volatile("s_waitcnt vmcnt(0)" ::: "memory");
  __syncthreads();

  // ---- epilogue ----
  float* sT1f = (float*)&sbuf[0][0];
  float* sT2f = sT1f + 256;
  if (tid < 256) sT1f[tid] = t1[bz * NDIM + bn0 + tid] + bb[0];
  else           sT2f[tid - 256] = t2[bz * NDIM + bm0 + (tid - 256)] + bc[0];
  __syncthreads();

  const int lr4 = fs * 4;
  if (write_f32) {
    #pragma unroll
    for (int m = 0; m < 8; ++m) {
      const int oo = wr * 128 + m * 16 + lr4;
      const int o  = bm0 + oo;
      #pragma unroll
      for (int n = 0; n < 4; ++n) {
        const int nn = wc * 64 + n * 16 + fr;
        const int ng = bn0 + nn;
        const float tz1  = sT1f[nn];
        const float bval = bias[ng];
        #pragma unroll
        for (int r = 0; r < 4; ++r) {
          float z = tz1 + sT2f[oo + r];
          z = z >= 0.f ? z : 0.2f * z;
          float coef = __expf(z - S[(size_t)(o + r) * NDIM + ng]);
          outF[(size_t)bz * NDIM * NDIM + (size_t)(o + r) * NDIM + ng] =
              fmaf(coef, acc[m][n][r], bval);
        }
      }
    }
  } else {
    float tp1[4] = {0.f, 0.f, 0.f, 0.f}, tp2[4] = {0.f, 0.f, 0.f, 0.f};
    #pragma unroll
    for (int m = 0; m < 8; ++m) {
      const int oo = wr * 128 + m * 16 + lr4;
      const int o  = bm0 + oo;
      float w1[4], w2[4];
      #pragma unroll
      for (int r = 0; r < 4; ++r) { w1[r] = wbe[o + r]; w2[r] = wce[o + r]; }
      #pragma unroll
      for (int n = 0; n < 4; ++n) {
        const int nn = wc * 64 + n * 16 + fr;
        const int ng = bn0 + nn;
        const float tz1  = sT1f[nn];
        const float bval = bias[ng];
        u16x4 wv;
        #pragma unroll
        for (int r = 0; r < 4; ++r) {
          float z = tz1 + sT2f[oo + r];
          z = z >= 0.f ? z : 0.2f * z;
          float coef = __expf(z - S[(size_t)(o + r) * NDIM + ng]);
          float val  = fmaf(coef, acc[m][n][r], bval);
          wv[r] = f2bf(val);
          tp1[n] = fmaf(w1[r], val, tp1[n]);
          tp2[n] = fmaf(w2[r], val, tp2[n]);
        }
        *(u16x4*)&outT[(size_t)bz * NDIM * NDIM + (size_t)ng * NDIM + o] = wv;
      }
    }
    #pragma unroll
    for (int n = 0; n < 4; ++n) {
      float a1 = tp1[n], a2 = tp2[n];
      a1 += __shfl_xor(a1, 16); a1 += __shfl_xor(a1, 32);
      a2 += __shfl_xor(a2, 16); a2 += __shfl_xor(a2, 32);
      if (fs == 0) {
        const int ng = bn0 + wc * 64 + n * 16 + fr;
        atomicAdd(&t1o[(size_t)bz * NDIM + ng], a1);
        atomicAdd(&t2o[(size_t)bz * NDIM + ng], a2);
      }
    }
  }
}

extern "C" void kernel_launch(void* const* d_in, const int* in_sizes, int n_in,
                              void* d_out, int out_size, void* d_ws, size_t ws_size,
                              hipStream_t stream) {
  const float* x    = (const float*)d_in[0];
  const float* Wa   = (const float*)d_in[1];
  const float* Wb   = (const float*)d_in[2];
  const float* bb   = (const float*)d_in[3];
  const float* Wc   = (const float*)d_in[4];
  const float* bc   = (const float*)d_in[5];
  const float* bias = (const float*)d_in[6];
  float* out = (float*)d_out;

  char* ws = (char*)d_ws;
  unsigned short* curA = (unsigned short*)ws; ws += (size_t)BDIM * NDIM * NDIM * 2;
  unsigned short* curB = (unsigned short*)ws; ws += (size_t)BDIM * NDIM * NDIM * 2;
  unsigned short* Apk  = (unsigned short*)ws; ws += (size_t)NDIM * NDIM * 2;
  float* t1a  = (float*)ws; ws += (size_t)BDIM * NDIM * 4;
  float* t2a  = (float*)ws; ws += (size_t)BDIM * NDIM * 4;
  float* t1b  = (float*)ws; ws += (size_t)BDIM * NDIM * 4;
  float* t2b  = (float*)ws; ws += (size_t)BDIM * NDIM * 4;
  float* wbe  = (float*)ws; ws += NDIM * 4;
  float* wce  = (float*)ws; ws += NDIM * 4;
  float* part = (float*)ws; ws += (size_t)32 * NDIM * 4;
  float* S    = (float*)ws; ws += (size_t)NDIM * NDIM * 4;

  // t1a..t2b are contiguous: one memset
  hipMemsetAsync(t1a, 0, (size_t)4 * BDIM * NDIM * 4, stream);

  pack_a<<<2048, 256, 0, stream>>>(Wa, Apk);
  weff1<<<dim3(8, 16), 256, 0, stream>>>(Wa, Wb, Wc, part);
  weff2<<<8, 256, 0, stream>>>(part, wbe, wce);
  transpose_convert<<<dim3(32, 32, BDIM), 256, 0, stream>>>(x, curA, wbe, wce, t1a, t2a);

  // step 0: curA -> curB (bf16 transposed), accumulate t1b/t2b
  s_kernel<<<dim3(NDIM / 256, NDIM), 256, 0, stream>>>(t1a, t2a, bb, bc, S);
  gemm_fused<<<dim3(8, 8, BDIM), 512, 0, stream>>>(
      Apk, curA, t1a, t2a, bb, bc, S, bias, wbe, wce, t1b, t2b, curB, out, 0);

  // step 1: curB -> out (f32)
  s_kernel<<<dim3(NDIM / 256, NDIM), 256, 0, stream>>>(t1b, t2b, bb, bc, S);
  gemm_fused<<<dim3(8, 8, BDIM), 512, 0, stream>>>(
      Apk, curB, t1b, t2b, bb, bc, S, bias, wbe, wce, t1a, t2a, curB, out, 1);
}